// Round 7
// baseline (117.805 us; speedup 1.0000x reference)
//
#include <hip/hip_runtime.h>

// PmLIF membrane recurrence, T timesteps, state in registers.
// Bit-exact vs the reference f32 op order:
//   t = x - v                      (one rounding; == -(v-0)+x )
//   h = v + inv_tau * t            (mul rounded, add rounded — NO fma fusion)
//   s = (h - v_th) > 0 ? 1 : 0
//   v = s ? 0 : h                  (v_reset = 0; select is exact)
//
// R7: deepen the register ring to PF=16 (float2 lanes, 32 waves/CU).
// Rationale: at 32 waves/CU the remaining gap to the copy ceiling is read-
// stream burstiness — each wave stalls on load t every iteration, so average
// outstanding-read depth < nominal. PF=16 doubles issue->consume slack.
// VGPR: 16*2 buf + ~15 overhead < 64, so __launch_bounds__(256,8) keeps all
// 8 blocks/CU resident.

constexpr int T_STEPS = 64;
constexpr int PF      = 16;          // prefetch depth == inner unroll
constexpr int NGRP    = T_STEPS / PF;

typedef float f32x2 __attribute__((ext_vector_type(2)));

struct StepOut { float v; float s; };

__device__ __forceinline__ StepOut pmlif_step(float xv, float v,
                                              float inv_tau, float v_th) {
    const float t = __fsub_rn(xv, v);
    const float h = __fadd_rn(v, __fmul_rn(inv_tau, t));
    const float u = __fsub_rn(h, v_th);
    const bool  b = u > 0.0f;
    StepOut r;
    r.s = b ? 1.0f : 0.0f;
    r.v = b ? 0.0f : h;
    return r;
}

__global__ __launch_bounds__(256, 8) void pmlif_scan_kernel(
    const f32x2* __restrict__ x,       // [T][n2]
    f32x2* __restrict__ out,           // [T][n2]
    const float* __restrict__ v_th_p,  // scalar
    const float* __restrict__ tau_p,   // scalar
    int n2)                            // (B*N)/2
{
    const int idx = blockIdx.x * blockDim.x + threadIdx.x;
    if (idx >= n2) return;

    const float v_th    = *v_th_p;
    const float inv_tau = __fdiv_rn(1.0f, *tau_p);

    const f32x2* __restrict__ xp = x + idx;
    f32x2* __restrict__ op = out + idx;
    const size_t step = (size_t)n2;

    // prologue: fill the ring
    f32x2 buf[PF];
#pragma unroll
    for (int k = 0; k < PF; ++k)
        buf[k] = __builtin_nontemporal_load(&xp[(size_t)k * step]);

    float v0 = 0.f, v1 = 0.f;

    // main: groups 0..NGRP-2 prefetch the next group
    for (int g = 0; g < NGRP - 1; ++g) {
        const f32x2* __restrict__ xg = xp + (size_t)(g + 1) * PF * step;
        f32x2* __restrict__ og = op + (size_t)g * PF * step;
#pragma unroll
        for (int k = 0; k < PF; ++k) {
            const f32x2 xv = buf[k];
            buf[k] = __builtin_nontemporal_load(&xg[(size_t)k * step]);
            const StepOut r0 = pmlif_step(xv.x, v0, inv_tau, v_th);
            const StepOut r1 = pmlif_step(xv.y, v1, inv_tau, v_th);
            v0 = r0.v; v1 = r1.v;
            f32x2 s; s.x = r0.s; s.y = r1.s;
            __builtin_nontemporal_store(s, &og[(size_t)k * step]);
        }
    }

    // tail group: no prefetch
    {
        f32x2* __restrict__ og = op + (size_t)(NGRP - 1) * PF * step;
#pragma unroll
        for (int k = 0; k < PF; ++k) {
            const f32x2 xv = buf[k];
            const StepOut r0 = pmlif_step(xv.x, v0, inv_tau, v_th);
            const StepOut r1 = pmlif_step(xv.y, v1, inv_tau, v_th);
            v0 = r0.v; v1 = r1.v;
            f32x2 s; s.x = r0.s; s.y = r1.s;
            __builtin_nontemporal_store(s, &og[(size_t)k * step]);
        }
    }
}

extern "C" void kernel_launch(void* const* d_in, const int* in_sizes, int n_in,
                              void* d_out, int out_size, void* d_ws, size_t ws_size,
                              hipStream_t stream) {
    const float* x    = (const float*)d_in[0];
    const float* v_th = (const float*)d_in[1];
    const float* tau  = (const float*)d_in[2];
    float* out = (float*)d_out;

    const int total = in_sizes[0];            // T * B * N
    const int bn    = total / T_STEPS;        // B * N (inner, contiguous)
    const int n2    = bn / 2;                 // float2 granularity

    const int block = 256;
    const int grid  = (n2 + block - 1) / block;

    pmlif_scan_kernel<<<grid, block, 0, stream>>>(
        (const f32x2*)x, (f32x2*)out, v_th, tau, n2);
}

// Round 8
// 103.576 us; speedup vs baseline: 1.1374x; 1.1374x over previous
//
#include <hip/hip_runtime.h>

// PmLIF membrane recurrence, T timesteps, state in registers.
// Bit-exact vs the reference f32 op order:
//   t = x - v                      (one rounding; == -(v-0)+x )
//   h = v + inv_tau * t            (mul rounded, add rounded — NO fma fusion)
//   s = (h - v_th) > 0 ? 1 : 0
//   v = s ? 0 : h                  (v_reset = 0; select is exact)
//
// R8: group-double-buffered issue order to beat in-order vmcnt retirement.
// Per group of 8 timesteps: [burst-issue 8 loads for group g+1 into the
// alternate buffer] -> [wait+compute group g, storing each step] .
// Every waited-on load now has only LOADS older than it in the vmcnt
// queue (prior group's stores were issued after it), so a load-wait never
// drains the store queue. float2 lanes, 2048 blocks = 8 blocks/CU,
// __launch_bounds__(256,8): bufA+bufB = 32 VGPR + ~15 overhead < 64 cap
// (R7 lesson: PF=16 single ring spilled past the cap and regressed).

constexpr int T_STEPS = 64;
constexpr int PF      = 8;           // group size == buffer depth
constexpr int NGRP    = T_STEPS / PF;

typedef float f32x2 __attribute__((ext_vector_type(2)));

struct StepOut { float v; float s; };

__device__ __forceinline__ StepOut pmlif_step(float xv, float v,
                                              float inv_tau, float v_th) {
    const float t = __fsub_rn(xv, v);
    const float h = __fadd_rn(v, __fmul_rn(inv_tau, t));
    const float u = __fsub_rn(h, v_th);
    const bool  b = u > 0.0f;
    StepOut r;
    r.s = b ? 1.0f : 0.0f;
    r.v = b ? 0.0f : h;
    return r;
}

__global__ __launch_bounds__(256, 8) void pmlif_scan_kernel(
    const f32x2* __restrict__ x,       // [T][n2]
    f32x2* __restrict__ out,           // [T][n2]
    const float* __restrict__ v_th_p,  // scalar
    const float* __restrict__ tau_p,   // scalar
    int n2)                            // (B*N)/2
{
    const int idx = blockIdx.x * blockDim.x + threadIdx.x;
    if (idx >= n2) return;

    const float v_th    = *v_th_p;
    const float inv_tau = __fdiv_rn(1.0f, *tau_p);

    const f32x2* __restrict__ xp = x + idx;
    f32x2* __restrict__ op = out + idx;
    const size_t step = (size_t)n2;

    f32x2 bufA[PF], bufB[PF];

    // prologue: group 0 into bufA
#pragma unroll
    for (int k = 0; k < PF; ++k)
        bufA[k] = __builtin_nontemporal_load(&xp[(size_t)k * step]);

    float v0 = 0.f, v1 = 0.f;

#pragma unroll
    for (int g = 0; g < NGRP; ++g) {
        // static buffer select (g is compile-time after full unroll)
        f32x2* cur = (g & 1) ? bufB : bufA;
        f32x2* nxt = (g & 1) ? bufA : bufB;

        // 1) burst-issue next group's loads BEFORE touching cur / stores
        if (g + 1 < NGRP) {
            const f32x2* __restrict__ xg = xp + (size_t)(g + 1) * PF * step;
#pragma unroll
            for (int k = 0; k < PF; ++k)
                nxt[k] = __builtin_nontemporal_load(&xg[(size_t)k * step]);
        }

        // 2) compute group g (waits only on loads; stores issued after)
        f32x2* __restrict__ og = op + (size_t)g * PF * step;
#pragma unroll
        for (int k = 0; k < PF; ++k) {
            const f32x2 xv = cur[k];
            const StepOut r0 = pmlif_step(xv.x, v0, inv_tau, v_th);
            const StepOut r1 = pmlif_step(xv.y, v1, inv_tau, v_th);
            v0 = r0.v; v1 = r1.v;
            f32x2 s; s.x = r0.s; s.y = r1.s;
            __builtin_nontemporal_store(s, &og[(size_t)k * step]);
        }
    }
}

extern "C" void kernel_launch(void* const* d_in, const int* in_sizes, int n_in,
                              void* d_out, int out_size, void* d_ws, size_t ws_size,
                              hipStream_t stream) {
    const float* x    = (const float*)d_in[0];
    const float* v_th = (const float*)d_in[1];
    const float* tau  = (const float*)d_in[2];
    float* out = (float*)d_out;

    const int total = in_sizes[0];            // T * B * N
    const int bn    = total / T_STEPS;        // B * N (inner, contiguous)
    const int n2    = bn / 2;                 // float2 granularity

    const int block = 256;
    const int grid  = (n2 + block - 1) / block;

    pmlif_scan_kernel<<<grid, block, 0, stream>>>(
        (const f32x2*)x, (f32x2*)out, v_th, tau, n2);
}